// Round 3
// baseline (650.557 us; speedup 1.0000x reference)
//
#include <hip/hip_runtime.h>

// Problem: B=64, C=256, H=W=56, HEADS=16, DH=16, WS=7, n1=n2=8, eps=1e-6
// Round-3: fragment-ordered dataflow.
//  - k0: weights f32 -> bf16 packed in MFMA B-frag order W2[head][kb][ks][nt][l15][quad][8]
//        so k2 loads each B-frag as ONE contiguous 1KB wave-load from L2 (no sB, no repack).
//  - k1: rebuilt. Block = (image, channel-octet): reads 8 FULL contiguous channel planes
//        (12.5KB each -- replaces the old 224B@12.5KB-stride pattern that ran at 1.2 TB/s),
//        BN+pack in LDS [8ch][3136px], then writes A2 in MFMA A-frag order
//        A2[tile][kb][ks][mt][l15][quad][8] as 16B/lane stores (L2-merged: the 32
//        octet-sibling blocks are co-XCD via swizzle).
//  - k2: stages the whole 32KB window A-tile ONCE (linear copy; frag-layout ds_reads are
//        conflict-free by construction), B-frags direct global->reg (L2-hot 0.4MB),
//        8 K-steps with no per-step barriers (2 barriers total). LDS 32KB -> 5 blocks/CU.
//        Epilogue/attention identical to round-2, overlaid on the dead A-tile.
// A2 pad rows (49..63 per tile) are uninitialized: NaN there only reaches masked
// output rows (A-row locality of MFMA + kt<49 selects); the PV 0*NaN hazard is
// closed by zeroing pv[1..3] at mt=3 and predicating vf[3] to quad0.
// Workspace: W2 0.39MB + A2 2MB/image (chunks batch if ws is tight).

typedef unsigned short u16;
typedef __attribute__((ext_vector_type(4))) float f32x4;
typedef __attribute__((ext_vector_type(8))) short short8;
typedef __attribute__((ext_vector_type(4))) short short4b;

__device__ __forceinline__ u16 f2bf(float f) {
  union { float f; unsigned int i; } v; v.f = f;
  unsigned int r = v.i + 0x7fffu + ((v.i >> 16) & 1u);   // RNE
  return (u16)(r >> 16);
}

// K0: pack weights to bf16 in B-fragment order.
// W2[head(16)][kb(4)][ks(2)][nt(3)][l15(16)][quad(4)][8ch], 16B per task.
// Linear task idx == frag offset/8 (verified: idx = (head*24+(kb*2+ks)*3+nt)*64+lq).
__global__ __launch_bounds__(256) void k0_wpack(
    const float* __restrict__ qkw, const float* __restrict__ vw,
    u16* __restrict__ w2)
{
  int idx = blockIdx.x * 256 + threadIdx.x;          // 24576 tasks
  int head = idx / 1536, r = idx - head * 1536;
  int kb = r / 384;  r -= kb * 384;
  int ks = r / 192;  r -= ks * 192;
  int nt = r / 64;   int lq = r - nt * 64;
  int l15 = lq >> 2, quad = lq & 3;
  const float* src;
  if (nt == 0)      src = qkw + (size_t)(head * 16 + l15) * 256;
  else if (nt == 1) src = qkw + (size_t)(256 + head * 16 + l15) * 256;
  else              src = vw  + (size_t)(head * 16 + l15) * 256;
  src += kb * 64 + ks * 32 + quad * 8;
  float4 a = *(const float4*)src;
  float4 c = *(const float4*)(src + 4);
  uint4 pk;
  pk.x = (unsigned)f2bf(a.x) | ((unsigned)f2bf(a.y) << 16);
  pk.y = (unsigned)f2bf(a.z) | ((unsigned)f2bf(a.w) << 16);
  pk.z = (unsigned)f2bf(c.x) | ((unsigned)f2bf(c.y) << 16);
  pk.w = (unsigned)f2bf(c.z) | ((unsigned)f2bf(c.w) << 16);
  *(uint4*)(w2 + (size_t)idx * 8) = pk;
}

// K1: BN + window-gather -> A2 frag order. Block = (image, channel-octet).
// Phase 1: stream 8 contiguous channel planes -> LDS [8][3136] bf16 (BN'd).
// Phase 2: per token, gather 8 channels -> one 16B store into A2 frag slot.
// Swizzle: 32 octet-siblings of an image land on one XCD so L2 merges the
// 16B-at-64B-stride frag writes into full lines.
__global__ __launch_bounds__(256) void k1_bn_pack(
    const float* __restrict__ x, const float* __restrict__ g,
    const float* __restrict__ be, const float* __restrict__ mu,
    const float* __restrict__ va, u16* __restrict__ a2, int b0)
{
  __shared__ u16 lds[8 * 3136];      // 50176 B -> 3 blocks/CU
  __shared__ float sbn[16];
  const int tid = threadIdx.x;
  const int bid = blockIdx.x;
  const int cpx = gridDim.x >> 3;                 // grid = nimg*32, %8==0
  const int L = (bid & 7) * cpx + (bid >> 3);
  const int coct = L & 31, bloc = L >> 5;
  const int b = b0 + bloc;
  const int c0 = coct * 8;

  if (tid < 8) {
    int c = c0 + tid;
    float inv = g[c] * rsqrtf(va[c] + 1e-6f);
    sbn[tid * 2] = inv;
    sbn[tid * 2 + 1] = be[c] - mu[c] * inv;
  }
  __syncthreads();

  const float* xp = x + (size_t)(b * 256 + c0) * 3136;
  for (int i = tid; i < 6272; i += 256) {          // 8 ch x 784 float4
    int cl = i / 784, q = i - cl * 784;
    float4 v = *(const float4*)(xp + (size_t)cl * 3136 + q * 4);
    float inv = sbn[cl * 2], sh = sbn[cl * 2 + 1];
    uint2 pk;
    pk.x = (unsigned)f2bf(fmaf(v.x, inv, sh)) |
           ((unsigned)f2bf(fmaf(v.y, inv, sh)) << 16);
    pk.y = (unsigned)f2bf(fmaf(v.z, inv, sh)) |
           ((unsigned)f2bf(fmaf(v.w, inv, sh)) << 16);
    *(uint2*)&lds[cl * 3136 + q * 4] = pk;
  }
  __syncthreads();

  const int kb = coct >> 3, ks = (coct >> 2) & 1, quad = coct & 3;
  const int fo = (kb * 2 + ks) * 4;
  u16* abase = a2 + (size_t)bloc * 64 * 16384;
  for (int i = tid; i < 3136; i += 256) {          // 64 win x 49 tok
    int win = i / 49, tok = i - win * 49;
    int wh = win >> 3, ww = win & 7;
    int wsh = tok / 7, wsw = tok - wsh * 7;
    int px = (wsh * 8 + wh) * 56 + wsw * 8 + ww;
    int mt = tok >> 4, l15 = tok & 15;
    u16 e0 = lds[0 * 3136 + px], e1 = lds[1 * 3136 + px];
    u16 e2 = lds[2 * 3136 + px], e3 = lds[3 * 3136 + px];
    u16 e4 = lds[4 * 3136 + px], e5 = lds[5 * 3136 + px];
    u16 e6 = lds[6 * 3136 + px], e7 = lds[7 * 3136 + px];
    uint4 pk;
    pk.x = (unsigned)e0 | ((unsigned)e1 << 16);
    pk.y = (unsigned)e2 | ((unsigned)e3 << 16);
    pk.z = (unsigned)e4 | ((unsigned)e5 << 16);
    pk.w = (unsigned)e6 | ((unsigned)e7 << 16);
    *(uint4*)(abase + (size_t)win * 16384 +
              (fo + mt) * 512 + (l15 * 4 + quad) * 8) = pk;
  }
}

// K2: fused QKV GEMM + attention, fragment-direct.
// Block = (window, 4-head group), 4 waves = 4 heads. Stage A-tile (32KB, frag
// order, linear copy) once; loop 8 K-steps: 4 conflict-free ds_read_b128 (A) +
// 3 contiguous 1KB global loads (B, L2-hot) + 12 MFMA. Barriers: one after
// staging, one before the epilogue overlays the A-tile. Attention per-wave,
// unchanged from round-2 except NaN-safety on the V tail.
__global__ __launch_bounds__(256, 5) void k2_fused(
    const u16* __restrict__ a2, const u16* __restrict__ w2,
    float* __restrict__ out, int b0)
{
  __shared__ u16 smem[16448];          // 32KB A-tile (+64 slack for vf overread)
  const int tid = threadIdx.x;
  const int lane = tid & 63, wv = tid >> 6;
  const int l15 = lane & 15, quad = lane >> 4, kbase = quad * 4;
  const int bid = blockIdx.x;
  const int cpx = gridDim.x >> 3;                 // grid = nimg*256, %8==0
  const int L = (bid & 7) * cpx + (bid >> 3);
  const int ww = L & 7, nb = (L >> 3) & 3, whg = L >> 5;
  const int wh = whg & 7, bloc = whg >> 3;
  const int b = b0 + bloc;
  const int tloc = bloc * 64 + wh * 8 + ww;
  const int head = nb * 4 + wv;

  // ---- stage A-tile: 32KB linear copy (frag order preserved) ----
  const u16* asrc = a2 + (size_t)tloc * 16384;
#pragma unroll
  for (int it = 0; it < 8; ++it) {
    int chunk = it * 256 + tid;
    *(uint4*)&smem[chunk * 8] = *(const uint4*)(asrc + chunk * 8);
  }
  __syncthreads();

  // ---- GEMM: 8 K-steps, no barriers ----
  const int laneoff = (l15 * 4 + quad) * 8;
  const u16* wp = w2 + (size_t)head * 12288 + laneoff;
  f32x4 acc[4][3];
#pragma unroll
  for (int i = 0; i < 4; ++i)
#pragma unroll
    for (int j = 0; j < 3; ++j) acc[i][j] = (f32x4)(0.0f);

#pragma unroll
  for (int kb = 0; kb < 4; ++kb)
#pragma unroll
    for (int ks = 0; ks < 2; ++ks) {
      int fo = kb * 2 + ks;
      short8 bf[3], af[4];
#pragma unroll
      for (int nt = 0; nt < 3; ++nt)
        bf[nt] = *(const short8*)(wp + (fo * 3 + nt) * 512);
#pragma unroll
      for (int mt = 0; mt < 4; ++mt)
        af[mt] = *(const short8*)&smem[(fo * 4 + mt) * 512 + laneoff];
#pragma unroll
      for (int mt = 0; mt < 4; ++mt)
#pragma unroll
        for (int nt = 0; nt < 3; ++nt)
          acc[mt][nt] = __builtin_amdgcn_mfma_f32_16x16x32_bf16(
              af[mt], bf[nt], acc[mt][nt], 0, 0, 0);
    }
  __syncthreads();   // all waves done reading the A-tile; safe to overlay

  // ---- epilogue: acc -> wave-private LDS tiles (region = wv*4096 u16) ----
  // Q[64][20] @0, K[64][20] @1280, VT[16][52] @2560 (3392 u16 <= 4096).
  // Pad rows 49..63 may be NaN (uninit A2 pad) -- never read (Q/K) or
  // explicitly zeroed (VT cols 49..51 via pv tail).
  u16* Qh = smem + wv * 4096;
  u16* Kh = Qh + 1280;
  u16* Vh = Kh + 1280;
#pragma unroll
  for (int mt = 0; mt < 4; ++mt) {
#pragma unroll
    for (int r = 0; r < 4; ++r) {
      int tok = mt * 16 + kbase + r;
      Qh[tok * 20 + l15] = f2bf(acc[mt][0][r]);
      Kh[tok * 20 + l15] = f2bf(acc[mt][1][r]);
    }
    int tok0 = mt * 16 + kbase;
    if (mt < 3) {
      short4b pv;
#pragma unroll
      for (int r = 0; r < 4; ++r) pv[r] = (short)f2bf(fmaxf(acc[mt][2][r], 0.0f));
      *(short4b*)&Vh[l15 * 52 + tok0] = pv;
    } else if (quad == 0) {
      short4b pv;                      // col 48 real; 49..51 MUST be 0 (0*NaN guard)
      pv[0] = (short)f2bf(fmaxf(acc[mt][2][0], 0.0f));
      pv[1] = 0; pv[2] = 0; pv[3] = 0;
      *(short4b*)&Vh[l15 * 52 + tok0] = pv;
    }
  }

  // ---- attention (wave-private; compiler orders own ds write->read) ----
  const float SM = 0.36067376022224085f;          // dh^-0.5 * log2(e)
  short4b ka[4], vf[4];
#pragma unroll
  for (int t = 0; t < 4; ++t) {
    ka[t] = *(const short4b*)&Kh[(t * 16 + l15) * 20 + kbase];
    if (t < 3)
      vf[t] = *(const short4b*)&Vh[l15 * 52 + t * 16 + kbase];
    else if (quad == 0)
      vf[t] = *(const short4b*)&Vh[l15 * 52 + 48];  // cols 48..51, tail zeroed
    else
      vf[t] = (short4b)0;              // ktok 52..63: pf=0, keep operand finite
  }
  f32x4 zz = (f32x4)(0.0f);
  const size_t obase0 = (size_t)(b * 256 + nb * 64 + wv * 16) * 3136;

#pragma unroll
  for (int qh = 0; qh < 2; ++qh) {               // q-split: bounds VGPR peak
    short4b qb[2];
#pragma unroll
    for (int ntl = 0; ntl < 2; ++ntl)
      qb[ntl] = *(const short4b*)&Qh[((qh * 2 + ntl) * 16 + l15) * 20 + kbase];

    f32x4 s[4][2];                     // S^T tiles: [mt over ktok][ntl over q]
#pragma unroll
    for (int mt = 0; mt < 4; ++mt)
#pragma unroll
      for (int ntl = 0; ntl < 2; ++ntl)
        s[mt][ntl] = __builtin_amdgcn_mfma_f32_16x16x16bf16_1k(
            ka[mt], qb[ntl], zz, 0, 0, 0);

    float inv_sum[2];
    short4b pf[4][2];                  // P^T frags == B-operand layout
#pragma unroll
    for (int ntl = 0; ntl < 2; ++ntl) {
      float m = -1e30f;
#pragma unroll
      for (int mt = 0; mt < 4; ++mt)
#pragma unroll
        for (int r = 0; r < 4; ++r) {
          int kt = mt * 16 + kbase + r;
          float v = (kt < 49) ? s[mt][ntl][r] : -1e30f;
          m = fmaxf(m, v);
        }
      m = fmaxf(m, __shfl_xor(m, 16, 64));
      m = fmaxf(m, __shfl_xor(m, 32, 64));
      float sum = 0.0f;
#pragma unroll
      for (int mt = 0; mt < 4; ++mt)
#pragma unroll
        for (int r = 0; r < 4; ++r) {
          int kt = mt * 16 + kbase + r;
          float p = (kt < 49) ? exp2f((s[mt][ntl][r] - m) * SM) : 0.0f;
          sum += p;
          pf[mt][ntl][r] = (short)f2bf(p);
        }
      sum += __shfl_xor(sum, 16, 64);
      sum += __shfl_xor(sum, 32, 64);
      inv_sum[ntl] = 1.0f / sum;       // defer normalize to store
    }

    f32x4 o[2];
#pragma unroll
    for (int ntl = 0; ntl < 2; ++ntl) o[ntl] = zz;
#pragma unroll
    for (int kt = 0; kt < 4; ++kt)
#pragma unroll
      for (int ntl = 0; ntl < 2; ++ntl)
        o[ntl] = __builtin_amdgcn_mfma_f32_16x16x16bf16_1k(
            vf[kt], pf[kt][ntl], o[ntl], 0, 0, 0);

    // direct store: lane holds O[q=qh*32+ntl*16+l15][d=kbase+r]
#pragma unroll
    for (int ntl = 0; ntl < 2; ++ntl) {
      int q = qh * 32 + ntl * 16 + l15;
      if (q < 49) {
        int tsh = q / 7, tsw = q - tsh * 7;
        size_t pbase = obase0 + (size_t)(tsh * 8 + wh) * 56 + tsw * 8 + ww;
#pragma unroll
        for (int r = 0; r < 4; ++r)
          out[pbase + (size_t)(kbase + r) * 3136] = o[ntl][r] * inv_sum[ntl];
      }
    }
  }
}

extern "C" void kernel_launch(void* const* d_in, const int* in_sizes, int n_in,
                              void* d_out, int out_size, void* d_ws, size_t ws_size,
                              hipStream_t stream) {
  const float* x   = (const float*)d_in[0];
  const float* g   = (const float*)d_in[1];
  const float* be  = (const float*)d_in[2];
  const float* mu  = (const float*)d_in[3];
  const float* va  = (const float*)d_in[4];
  const float* qkw = (const float*)d_in[5];
  const float* vw  = (const float*)d_in[6];
  float* outp = (float*)d_out;

  const size_t W2_BYTES = (size_t)768 * 256 * 2;        // 0.39 MB frag weights
  const size_t PER_IMG  = (size_t)64 * 16384 * 2;       // 2 MB A2 per image
  u16* w2 = (u16*)d_ws;
  u16* a2 = (u16*)((char*)d_ws + W2_BYTES);

  size_t avail = ws_size > W2_BYTES ? ws_size - W2_BYTES : 0;
  int bchunk = (int)(avail / PER_IMG);
  if (bchunk > 64) bchunk = 64;
  if (bchunk < 1)  bchunk = 1;    // needs only ~2.4 MB of workspace

  k0_wpack<<<96, 256, 0, stream>>>(qkw, vw, w2);
  for (int c = 0; c < 64; c += bchunk) {
    int nb = (64 - c < bchunk) ? (64 - c) : bchunk;
    k1_bn_pack<<<nb * 32, 256, 0, stream>>>(x, g, be, mu, va, a2, c);
    k2_fused<<<nb * 256, 256, 0, stream>>>(a2, w2, outp, c);
  }
}

// Round 4
// 568.093 us; speedup vs baseline: 1.1452x; 1.1452x over previous
//
#include <hip/hip_runtime.h>

// Problem: B=64, C=256, H=W=56, HEADS=16, DH=16, WS=7, n1=n2=8, eps=1e-6
// Round-4: both round-3 rewrites regressed; root causes and fixes:
//  - k2: per-K-step global B loads exposed L2 latency (no prefetch depth at
//    60 VGPR) -> REVERT to round-2's measured-258us kernel (LDS-staged B,
//    barrier-amortized), changing ONLY the A-staging addressing.
//  - k1: frag-order writes were 16B@64B-stride (25% line fill, 4-block L2
//    merge) -> new A layout aws2[coct(32)][token(200704)][8ch] makes BOTH
//    sides of k1 perfectly contiguous: reads = 8 full channel planes,
//    writes = 64 consecutive tokens x 16B = 1KB/wave. k2's A-stage reads
//    become 1KB-contiguous slab loads (better than round-2's 128B segments).
// Clamp row>=49 -> 48 kept in k2 staging => acc bit-identical to round 2.
// Workspace: aws2 98MB + wb 0.4MB (same budget as round 2, no chunking).

typedef unsigned short u16;
typedef __attribute__((ext_vector_type(4))) float f32x4;
typedef __attribute__((ext_vector_type(8))) short short8;
typedef __attribute__((ext_vector_type(4))) short short4b;

__device__ __forceinline__ u16 f2bf(float f) {
  union { float f; unsigned int i; } v; v.f = f;
  unsigned int r = v.i + 0x7fffu + ((v.i >> 16) & 1u);   // RNE
  return (u16)(r >> 16);
}

// K0: pack weights to bf16 once, row-major wb[n][256]; row n = head*48+sub,
// sub 0..15 = q, 16..31 = k, 32..47 = v. (round-2 version, unchanged)
__global__ __launch_bounds__(256) void k0_wpack(
    const float* __restrict__ qkw, const float* __restrict__ vw,
    u16* __restrict__ wb)
{
  int idx = blockIdx.x * 256 + threadIdx.x;
  int n = idx >> 5, oct = idx & 31;
  int head = n / 48, sub = n - head * 48;
  const float* src;
  if (sub < 16)      src = qkw + (size_t)(head * 16 + sub) * 256;
  else if (sub < 32) src = qkw + (size_t)(256 + head * 16 + (sub - 16)) * 256;
  else               src = vw  + (size_t)(head * 16 + (sub - 32)) * 256;
  src += oct * 8;
  float4 a = *(const float4*)src;
  float4 c = *(const float4*)(src + 4);
  uint4 pk;
  pk.x = (unsigned)f2bf(a.x) | ((unsigned)f2bf(a.y) << 16);
  pk.y = (unsigned)f2bf(a.z) | ((unsigned)f2bf(a.w) << 16);
  pk.z = (unsigned)f2bf(c.x) | ((unsigned)f2bf(c.y) << 16);
  pk.w = (unsigned)f2bf(c.z) | ((unsigned)f2bf(c.w) << 16);
  *(uint4*)(wb + (size_t)n * 256 + oct * 8) = pk;
}

// K1: BN + window-gather -> aws2[coct][gtok][8] bf16. Block = (image, c-octet).
// Phase 1: stream 8 contiguous channel planes -> LDS [8][3136] bf16 (BN'd).
// Phase 2: lane handles token i: gather 8 channels from LDS, ONE 16B store at
// abase + i*8 -> consecutive lanes contiguous (1KB/wave). Both phases stream.
__global__ __launch_bounds__(256) void k1_bn_oct(
    const float* __restrict__ x, const float* __restrict__ g,
    const float* __restrict__ be, const float* __restrict__ mu,
    const float* __restrict__ va, u16* __restrict__ aws2)
{
  __shared__ u16 lds[8 * 3136];      // 50176 B -> 3 blocks/CU
  __shared__ float sbn[16];
  const int tid = threadIdx.x;
  const int bid = blockIdx.x;
  const int b = bid >> 5, coct = bid & 31;
  const int c0 = coct * 8;

  if (tid < 8) {
    int c = c0 + tid;
    float inv = g[c] * rsqrtf(va[c] + 1e-6f);
    sbn[tid * 2] = inv;
    sbn[tid * 2 + 1] = be[c] - mu[c] * inv;
  }
  __syncthreads();

  const float* xp = x + (size_t)(b * 256 + c0) * 3136;
  for (int i = tid; i < 6272; i += 256) {          // 8 ch x 784 float4
    int cl = i / 784, q = i - cl * 784;
    float4 v = *(const float4*)(xp + (size_t)cl * 3136 + q * 4);
    float inv = sbn[cl * 2], sh = sbn[cl * 2 + 1];
    uint2 pk;
    pk.x = (unsigned)f2bf(fmaf(v.x, inv, sh)) |
           ((unsigned)f2bf(fmaf(v.y, inv, sh)) << 16);
    pk.y = (unsigned)f2bf(fmaf(v.z, inv, sh)) |
           ((unsigned)f2bf(fmaf(v.w, inv, sh)) << 16);
    *(uint2*)&lds[cl * 3136 + q * 4] = pk;
  }
  __syncthreads();

  // token i = win*49+tok; global row = b*3136 + i (matches k2's tloc*49+tok)
  u16* abase = aws2 + ((size_t)coct * 200704 + (size_t)b * 3136) * 8;
  for (int i = tid; i < 3136; i += 256) {
    int win = i / 49, tok = i - win * 49;
    int wh = win >> 3, ww = win & 7;
    int wsh = tok / 7, wsw = tok - wsh * 7;
    int px = (wsh * 8 + wh) * 56 + wsw * 8 + ww;
    u16 e0 = lds[0 * 3136 + px], e1 = lds[1 * 3136 + px];
    u16 e2 = lds[2 * 3136 + px], e3 = lds[3 * 3136 + px];
    u16 e4 = lds[4 * 3136 + px], e5 = lds[5 * 3136 + px];
    u16 e6 = lds[6 * 3136 + px], e7 = lds[7 * 3136 + px];
    uint4 pk;
    pk.x = (unsigned)e0 | ((unsigned)e1 << 16);
    pk.y = (unsigned)e2 | ((unsigned)e3 << 16);
    pk.z = (unsigned)e4 | ((unsigned)e5 << 16);
    pk.w = (unsigned)e6 | ((unsigned)e7 << 16);
    *(uint4*)(abase + (size_t)i * 8) = pk;
  }
}

// K2: fused QKV GEMM + attention -- round-2 kernel (measured 258us), with
// A-staging re-addressed to the octet-major aws2 (1KB-contiguous wave loads).
// Block = (window, 4-head group), 4 waves = 4 heads; GEMM M=64 N=192 K=256,
// BK=64, LDS-staged A+B per kb; epilogue bounces Q/K/VT through dead LDS
// (wave-private, no barrier); per-wave attention; direct f32 stores with
// XCD-chunked swizzle for L2 write merging.
__global__ __launch_bounds__(256, 4) void k2_fused(
    const u16* __restrict__ aws2, const u16* __restrict__ wb,
    float* __restrict__ out)
{
  __shared__ u16 smem[18432];          // 36864 B -> 4 blocks/CU
  u16* sA = smem;                      // [64][72]
  u16* sB = smem + 4608;               // [192][72]
  const int tid = threadIdx.x;
  const int lane = tid & 63, wv = tid >> 6;
  const int l15 = lane & 15, quad = lane >> 4, kbase = quad * 4;

  // XCD-chunked swizzle: L consecutive => same XCD (bid%8 = xcd).
  // L inner->outer: ww(8), nb(4), wh(8), b(64): output-row siblings (ww) and
  // A-panel siblings (nb) are co-XCD.
  const int bid = blockIdx.x;
  const int L = (bid & 7) * 2048 + (bid >> 3);
  const int ww = L & 7, nb = (L >> 3) & 3, whg = L >> 5;  // whg = b*8+wh
  const int wh = whg & 7, b = whg >> 3;
  const int tloc = (whg << 3) | ww;                        // b*64+wh*8+ww
  const int t0 = tloc * 49;
  const int nb0 = nb * 192;

  f32x4 acc[4][3];
#pragma unroll
  for (int i = 0; i < 4; ++i)
#pragma unroll
    for (int j = 0; j < 3; ++j) acc[i][j] = (f32x4)(0.0f);

  for (int kb = 0; kb < 4; ++kb) {
    __syncthreads();
    // stage A: 8 octet-slabs x 64 token rows, 1KB contiguous per 64-lane group
    // (rows >= 49 clamp to 48: bit-identical to round-2 acc; always in-bounds)
#pragma unroll
    for (int it = 0; it < 2; ++it) {
      int idx = it * 256 + tid;
      int oct = idx >> 6, r = idx & 63;
      int rs = r < 49 ? r : 48;
      uint4 v = *(const uint4*)(aws2 +
          ((size_t)(kb * 8 + oct) * 200704 + t0 + rs) * 8);
      *(uint4*)&sA[r * 72 + oct * 8] = v;
    }
    // stage B: 192 rows x 8 octets (bf16 weights, L2-resident)
#pragma unroll
    for (int it = 0; it < 6; ++it) {
      int idx = it * 256 + tid;
      int r = idx >> 3, oct = idx & 7;
      uint4 v = *(const uint4*)(wb + (size_t)(nb0 + r) * 256 + kb * 64 + oct * 8);
      *(uint4*)&sB[r * 72 + oct * 8] = v;
    }
    __syncthreads();
#pragma unroll
    for (int ks = 0; ks < 2; ++ks) {             // two K=32 steps
      int col = ks * 32 + quad * 8;
      short8 bf[3];
#pragma unroll
      for (int nt = 0; nt < 3; ++nt)
        bf[nt] = *(const short8*)&sB[(wv * 48 + nt * 16 + l15) * 72 + col];
#pragma unroll
      for (int mt = 0; mt < 4; ++mt) {
        short8 af = *(const short8*)&sA[(mt * 16 + l15) * 72 + col];
#pragma unroll
        for (int nt = 0; nt < 3; ++nt)
          acc[mt][nt] = __builtin_amdgcn_mfma_f32_16x16x32_bf16(
              af, bf[nt], acc[mt][nt], 0, 0, 0);
      }
    }
  }
  __syncthreads();   // sA/sB dead after this; regions below are wave-private

  // ---- epilogue: acc -> wave-private LDS tiles (no barrier needed after) ----
  // per-head region 3392 u16: Q[64][20] @0, K[64][20] @1280, VT[16][52] @2560.
  // Rows 49..63 are finite garbage (projections of clamped row 48) -- masked
  // downstream. Pitch 20 keeps writes 2-way-free.
  u16* Qh = smem + wv * 3392;
  u16* Kh = Qh + 1280;
  u16* Vh = Kh + 1280;
#pragma unroll
  for (int mt = 0; mt < 4; ++mt) {
#pragma unroll
    for (int r = 0; r < 4; ++r) {
      int tok = mt * 16 + kbase + r;
      Qh[tok * 20 + l15] = f2bf(acc[mt][0][r]);
      Kh[tok * 20 + l15] = f2bf(acc[mt][1][r]);
    }
    // VT[d=l15][tok]: one 8B store; mt=3 only quad 0 fits (cols 48..51,
    // 49..51 finite garbage, never unmasked).
    int tok0 = mt * 16 + kbase;
    if (mt < 3 || quad == 0) {
      short4b pv;
#pragma unroll
      for (int r = 0; r < 4; ++r) pv[r] = (short)f2bf(fmaxf(acc[mt][2][r], 0.0f));
      *(short4b*)&Vh[l15 * 52 + tok0] = pv;
    }
  }

  // ---- attention (wave-private; compiler orders own ds write->read) ----
  const float SM = 0.36067376022224085f;          // dh^-0.5 * log2(e)
  short4b ka[4], vf[4];
#pragma unroll
  for (int t = 0; t < 4; ++t) {
    ka[t] = *(const short4b*)&Kh[(t * 16 + l15) * 20 + kbase];
    // vf[3] quads 1..3 read past the VT row / region: finite stale LDS,
    // multiplied by pf=0 (ktok>=49 masked). quad0 col 48 is the real tail.
    vf[t] = *(const short4b*)&Vh[l15 * 52 + t * 16 + kbase];
  }
  f32x4 zz = (f32x4)(0.0f);
  const size_t obase0 = (size_t)(b * 256 + nb * 64 + wv * 16) * 3136;

#pragma unroll
  for (int qh = 0; qh < 2; ++qh) {               // q-split: bounds VGPR peak
    short4b qb[2];
#pragma unroll
    for (int ntl = 0; ntl < 2; ++ntl)
      qb[ntl] = *(const short4b*)&Qh[((qh * 2 + ntl) * 16 + l15) * 20 + kbase];

    f32x4 s[4][2];                     // S^T tiles: [mt over ktok][ntl over q]
#pragma unroll
    for (int mt = 0; mt < 4; ++mt)
#pragma unroll
      for (int ntl = 0; ntl < 2; ++ntl)
        s[mt][ntl] = __builtin_amdgcn_mfma_f32_16x16x16bf16_1k(
            ka[mt], qb[ntl], zz, 0, 0, 0);

    float inv_sum[2];
    short4b pf[4][2];                  // P^T frags == B-operand layout
#pragma unroll
    for (int ntl = 0; ntl < 2; ++ntl) {
      float m = -1e30f;
#pragma unroll
      for (int mt = 0; mt < 4; ++mt)
#pragma unroll
        for (int r = 0; r < 4; ++r) {
          int kt = mt * 16 + kbase + r;
          float v = (kt < 49) ? s[mt][ntl][r] : -1e30f;
          m = fmaxf(m, v);
        }
      m = fmaxf(m, __shfl_xor(m, 16, 64));
      m = fmaxf(m, __shfl_xor(m, 32, 64));
      float sum = 0.0f;
#pragma unroll
      for (int mt = 0; mt < 4; ++mt)
#pragma unroll
        for (int r = 0; r < 4; ++r) {
          int kt = mt * 16 + kbase + r;
          float p = (kt < 49) ? exp2f((s[mt][ntl][r] - m) * SM) : 0.0f;
          sum += p;
          pf[mt][ntl][r] = (short)f2bf(p);
        }
      sum += __shfl_xor(sum, 16, 64);
      sum += __shfl_xor(sum, 32, 64);
      inv_sum[ntl] = 1.0f / sum;       // defer normalize to store
    }

    f32x4 o[2];
#pragma unroll
    for (int ntl = 0; ntl < 2; ++ntl) o[ntl] = zz;
#pragma unroll
    for (int kt = 0; kt < 4; ++kt)
#pragma unroll
      for (int ntl = 0; ntl < 2; ++ntl)
        o[ntl] = __builtin_amdgcn_mfma_f32_16x16x16bf16_1k(
            vf[kt], pf[kt][ntl], o[ntl], 0, 0, 0);

    // direct store: lane holds O[q=qh*32+ntl*16+l15][d=kbase+r]
#pragma unroll
    for (int ntl = 0; ntl < 2; ++ntl) {
      int q = qh * 32 + ntl * 16 + l15;
      if (q < 49) {
        int tsh = q / 7, tsw = q - tsh * 7;
        size_t pbase = obase0 + (size_t)(tsh * 8 + wh) * 56 + tsw * 8 + ww;
#pragma unroll
        for (int r = 0; r < 4; ++r)
          out[pbase + (size_t)(kbase + r) * 3136] = o[ntl][r] * inv_sum[ntl];
      }
    }
  }
}

extern "C" void kernel_launch(void* const* d_in, const int* in_sizes, int n_in,
                              void* d_out, int out_size, void* d_ws, size_t ws_size,
                              hipStream_t stream) {
  const float* x   = (const float*)d_in[0];
  const float* g   = (const float*)d_in[1];
  const float* be  = (const float*)d_in[2];
  const float* mu  = (const float*)d_in[3];
  const float* va  = (const float*)d_in[4];
  const float* qkw = (const float*)d_in[5];
  const float* vw  = (const float*)d_in[6];
  float* outp = (float*)d_out;

  const size_t AWS2_BYTES = (size_t)32 * 200704 * 8 * 2;  // 98.0 MB
  u16* aws2 = (u16*)d_ws;
  u16* wb   = (u16*)((char*)d_ws + AWS2_BYTES);           // 0.39 MB weights

  k0_wpack<<<96, 256, 0, stream>>>(qkw, vw, wb);
  k1_bn_oct<<<64 * 32, 256, 0, stream>>>(x, g, be, mu, va, aws2);
  k2_fused<<<64 * 64 * 4, 256, 0, stream>>>(aws2, wb, outp);
}